// Round 19
// baseline (353.274 us; speedup 1.0000x reference)
//
#include <hip/hip_runtime.h>

#define NSEQ 512
#define DD 128
#define NP (NSEQ * NSEQ)

typedef unsigned short u16;
typedef __attribute__((ext_vector_type(8))) unsigned short u16x8;
typedef __attribute__((ext_vector_type(4))) unsigned short u16x4;
typedef __attribute__((ext_vector_type(8))) short bf16x8;
typedef __attribute__((ext_vector_type(4))) float f32x4;

__device__ __forceinline__ u16 f2bf(float f) {
  unsigned int x = __float_as_uint(f);
  return (u16)((x + 0x7fffu + ((x >> 16) & 1u)) >> 16);  // RNE
}
__device__ __forceinline__ float bf2f(u16 u) {
  return __uint_as_float(((unsigned int)u) << 16);
}
__device__ __forceinline__ f32x4 mfma16(bf16x8 a, bf16x8 b, f32x4 c) {
  return __builtin_amdgcn_mfma_f32_16x16x32_bf16(a, b, c, 0, 0, 0);
}
__device__ __forceinline__ void gload16(const void* g, void* l) {
  __builtin_amdgcn_global_load_lds(
      (const __attribute__((address_space(1))) unsigned int*)g,
      (__attribute__((address_space(3))) unsigned int*)l, 16, 0, 0);
}
__device__ __forceinline__ float rcp_(float v) { return __builtin_amdgcn_rcpf(v); }
__device__ __forceinline__ float rsq_(float v) { return __builtin_amdgcn_rsqf(v); }
__device__ __forceinline__ float sigmoidf_(float v) { return rcp_(1.f + __expf(-v)); }

// Layouts:
//  n1t/n2t: [posblk][h][64]   (kA writes 16-KB contiguous per block)
//  P:       [i][jb][h][jIn]   (kC block (i,jb) reads ONE contiguous 32-KB slab)
//  kB stages its tile in LDS and streams rows as 256-B contiguous wave-stores.
// Round 19: the n-loop (kA) and sub-loop (kC) were pinned at unroll 1 since round 8 —
// each iteration's ds_read -> MFMA chain -> sigmoid chain -> store ran fully serial.
// unroll 2 lets iter k+1's loads overlap iter k's compute chains.

// ---------------- weight prep: all six 128x128 matrices -> MFMA fragment order ----------
__global__ void kW(const float* __restrict__ wa, const float* __restrict__ wga,
                   const float* __restrict__ wb, const float* __restrict__ wgb,
                   const float* __restrict__ wg, const float* __restrict__ wo,
                   u16* __restrict__ Wp) {
  int b = blockIdx.x, t = threadIdx.x;
  int m = b >> 5, cf = (b >> 2) & 7, kf = b & 3;
  const float* m6[6] = {wa, wga, wb, wgb, wg, wo};
  const float* src = m6[m];
  int lane = t >> 1, e0 = (t & 1) * 4;
  u16* dst = Wp + m * 16384 + (cf * 4 + kf) * 512 + lane * 8 + e0;
  int col = cf * 16 + (lane & 15);
  int row0 = kf * 32 + (lane >> 4) * 8 + e0;
#pragma unroll
  for (int e = 0; e < 4; ++e) dst[e] = f2bf(src[(row0 + e) * 128 + col]);
}

// ---------------- kernel A: LN + 4 projections + gating -> n1t, n2t ------------------
__global__ void __launch_bounds__(256)
    __attribute__((amdgpu_waves_per_eu(4, 8)))
    kA(const float* __restrict__ x, const float* __restrict__ zn_s,
       const float* __restrict__ zn_b, const float* __restrict__ b_a,
       const float* __restrict__ b_ga, const float* __restrict__ b_b,
       const float* __restrict__ b_gb, const u16* __restrict__ Wp,
       u16* __restrict__ n1t, u16* __restrict__ n2t) {
  __shared__ __align__(16) u16 z[64 * 136];
  int tid = threadIdx.x;
  int pos0 = blockIdx.x * 64;
  int lane = tid & 63, w = tid >> 6;

  {  // single-pass LN: 4 threads per row (32 cols each), x held in registers
    int r = tid >> 2, part = tid & 3;
    const float* px = x + (size_t)pos0 * 128 + r * 128 + part * 32;
    float4 xv[8];
    float s = 0.f, s2 = 0.f;
#pragma unroll
    for (int q = 0; q < 8; ++q) {
      xv[q] = *(const float4*)(px + q * 4);
      s += xv[q].x + xv[q].y + xv[q].z + xv[q].w;
      s2 += xv[q].x * xv[q].x + xv[q].y * xv[q].y + xv[q].z * xv[q].z + xv[q].w * xv[q].w;
    }
    s += __shfl_xor(s, 1);
    s2 += __shfl_xor(s2, 1);
    s += __shfl_xor(s, 2);
    s2 += __shfl_xor(s2, 2);
    float mu = s * (1.f / 128.f);
    float rs = rsq_(s2 * (1.f / 128.f) - mu * mu + 1e-5f);
#pragma unroll
    for (int q = 0; q < 8; ++q) {
      int c0 = part * 32 + q * 4;
      u16x4 o;
      o[0] = f2bf((xv[q].x - mu) * rs * zn_s[c0 + 0] + zn_b[c0 + 0]);
      o[1] = f2bf((xv[q].y - mu) * rs * zn_s[c0 + 1] + zn_b[c0 + 1]);
      o[2] = f2bf((xv[q].z - mu) * rs * zn_s[c0 + 2] + zn_b[c0 + 2]);
      o[3] = f2bf((xv[q].w - mu) * rs * zn_s[c0 + 3] + zn_b[c0 + 3]);
      *(u16x4*)&z[r * 136 + c0] = o;
    }
  }
  __syncthreads();  // every wave reads all 64 z rows below

  int quad = lane >> 4, colL = lane & 15;
  size_t bbase = (size_t)blockIdx.x * 8192;  // this block's 16-KB output window

#pragma unroll 1
  for (int g = 0; g < 2; ++g) {
    const float* bxp = g ? b_b : b_a;
    const float* bgp = g ? b_gb : b_ga;
    u16* dst = g ? n2t : n1t;
    const u16* WxP = Wp + (g * 2) * 16384 + lane * 8;
    const u16* WgP = Wp + (g * 2 + 1) * 16384 + lane * 8;

    // hoisted: this wave's weight B-fragments (cf = 2w, 2w+1) and per-lane biases
    bf16x8 wxf[2][4], wgf[2][4];
    float bx[2], bg[2];
#pragma unroll
    for (int c2 = 0; c2 < 2; ++c2) {
      int cf = w * 2 + c2;
#pragma unroll
      for (int kf = 0; kf < 4; ++kf) {
        wxf[c2][kf] = *(const bf16x8*)&WxP[(cf * 4 + kf) * 512];
        wgf[c2][kf] = *(const bf16x8*)&WgP[(cf * 4 + kf) * 512];
      }
      int h = cf * 16 + colL;
      bx[c2] = bxp[h];
      bg[c2] = bgp[h];
    }

#pragma unroll 2
    for (int n = 0; n < 4; ++n) {
      bf16x8 zb[4];  // z A-fragments: row = n*16 + colL, k-chunk = quad
#pragma unroll
      for (int kf = 0; kf < 4; ++kf)
        zb[kf] = *(const bf16x8*)&z[(n * 16 + colL) * 136 + kf * 32 + quad * 8];
      f32x4 au0 = {0.f, 0.f, 0.f, 0.f}, au1 = au0, ag0 = au0, ag1 = au0;
#pragma unroll
      for (int kf = 0; kf < 4; ++kf) {
        au0 = mfma16(zb[kf], wxf[0][kf], au0);
        au1 = mfma16(zb[kf], wxf[1][kf], au1);
        ag0 = mfma16(zb[kf], wgf[0][kf], ag0);
        ag1 = mfma16(zb[kf], wgf[1][kf], ag1);
      }
      // D: row = quad*4 + r -> pos-in-block, col = colL -> h. [posblk][h][64] layout.
      int pin = n * 16 + quad * 4;
      int h0 = (w * 2) * 16 + colL;
      int h1 = (w * 2 + 1) * 16 + colL;
      u16x4 o0, o1;
#pragma unroll
      for (int r = 0; r < 4; ++r) {
        o0[r] = f2bf((au0[r] + bx[0]) * sigmoidf_(ag0[r] + bg[0]));
        o1[r] = f2bf((au1[r] + bx[1]) * sigmoidf_(ag1[r] + bg[1]));
      }
      *(u16x4*)&dst[bbase + h0 * 64 + pin] = o0;
      *(u16x4*)&dst[bbase + h1 * 64 + pin] = o1;
    }
  }
}

// ---------------- kernel B: per-h NT GEMM  P[i][jb][h][jIn] = sum_k n1.n2 ---------------
// LDS: SH[0..16383] = A double-buffer, SH[16384..32767] = B double-buffer; after the
// K-loop the whole 64 KB is dead and reused as the Pt staging tile [128][136].
__global__ __launch_bounds__(256) void kB(const u16* __restrict__ n1t,
                                          const u16* __restrict__ n2t,
                                          u16* __restrict__ P) {
  __shared__ __align__(16) u16 SH[32768];
  int bid = blockIdx.x;
  int h = bid >> 4, t = bid & 15;
  int i0 = (t >> 2) * 128, j0 = (t & 3) * 128, jb = t & 3;
  const u16* Ab = n1t + h * 64;
  const u16* Bb = n2t + h * 64;
  int tid = threadIdx.x, lane = tid & 63, w = tid >> 6;

  f32x4 acc[4][4];
#pragma unroll
  for (int a_ = 0; a_ < 4; ++a_)
#pragma unroll
    for (int b_ = 0; b_ < 4; ++b_) acc[a_][b_] = f32x4{0.f, 0.f, 0.f, 0.f};

  auto STAGE = [&](int buf, int kt) {
#pragma unroll
    for (int q = 0; q < 4; ++q) {
      int c = q * 256 + tid;
      int row = c >> 3, ch = c & 7;
      int chG = ch ^ (row & 7);
      gload16(Ab + (size_t)((i0 + row) * 8 + kt) * 8192 + chG * 8, &SH[buf * 8192 + c * 8]);
    }
#pragma unroll
    for (int q = 0; q < 4; ++q) {
      int c = q * 256 + tid;
      int row = c >> 3, ch = c & 7;
      int chG = ch ^ (row & 7);
      gload16(Bb + (size_t)((j0 + row) * 8 + kt) * 8192 + chG * 8,
              &SH[16384 + buf * 8192 + c * 8]);
    }
  };

  STAGE(0, 0);
  int cur = 0;
  int r0 = (w >> 1) * 64, c0 = (w & 1) * 64;
#pragma unroll 1
  for (int kt = 0; kt < 8; ++kt) {
    if (kt < 7) {
      STAGE(cur ^ 1, kt + 1);
      __builtin_amdgcn_sched_barrier(0);
      asm volatile("s_waitcnt vmcnt(8)" ::: "memory");
    } else {
      asm volatile("s_waitcnt vmcnt(0)" ::: "memory");
    }
    __builtin_amdgcn_sched_barrier(0);
    __builtin_amdgcn_s_barrier();
    __builtin_amdgcn_sched_barrier(0);
#pragma unroll
    for (int kf = 0; kf < 2; ++kf) {
      bf16x8 a[4], b[4];
#pragma unroll
      for (int rf = 0; rf < 4; ++rf) {
        int row = r0 + rf * 16 + (lane & 15);
        a[rf] = *(const bf16x8*)&SH[cur * 8192 + row * 64 +
                                    (((kf * 4 + (lane >> 4)) ^ (row & 7)) * 8)];
      }
#pragma unroll
      for (int cf = 0; cf < 4; ++cf) {
        int row = c0 + cf * 16 + (lane & 15);
        b[cf] = *(const bf16x8*)&SH[16384 + cur * 8192 + row * 64 +
                                    (((kf * 4 + (lane >> 4)) ^ (row & 7)) * 8)];
      }
#pragma unroll
      for (int rf = 0; rf < 4; ++rf)
#pragma unroll
        for (int cf = 0; cf < 4; ++cf) acc[rf][cf] = mfma16(a[rf], b[cf], acc[rf][cf]);
    }
    __builtin_amdgcn_sched_barrier(0);
    __builtin_amdgcn_s_barrier();
    __builtin_amdgcn_sched_barrier(0);
    cur ^= 1;
  }

  // ---- epilogue: stage tile in LDS, then stream 256-B contiguous wave-stores ----
#pragma unroll
  for (int rf = 0; rf < 4; ++rf)
#pragma unroll
    for (int cf = 0; cf < 4; ++cf) {
      int lrow = (w >> 1) * 64 + rf * 16 + (lane >> 4) * 4;
      int jIn = c0 + cf * 16 + (lane & 15);
#pragma unroll
      for (int r = 0; r < 4; ++r) SH[(lrow + r) * 136 + jIn] = f2bf(acc[rf][cf][r]);
    }
  __syncthreads();
#pragma unroll 1
  for (int lr8 = 0; lr8 < 32; ++lr8) {
    int lr = w * 32 + lr8;
    unsigned int v = *(const unsigned int*)&SH[lr * 136 + lane * 2];
    *(unsigned int*)&P[((size_t)(i0 + lr) * 4 + jb) * 16384 + h * 128 + lane * 2] = v;
  }
}

// ---------------- kernel C: LN over h, @w_o + b_o, * sigmoid(z@w_g + b_g) -----------------
__global__ void __launch_bounds__(256)
    __attribute__((amdgpu_waves_per_eu(4, 4)))
    kC(const float* __restrict__ x, const u16* __restrict__ P,
       const float* __restrict__ zn_s, const float* __restrict__ zn_b,
       const float* __restrict__ ln_s, const float* __restrict__ ln_b,
       const u16* __restrict__ Wp, const float* __restrict__ b_o,
       const float* __restrict__ b_g, float* __restrict__ out) {
  __shared__ __align__(16) u16 T[128 * 136];
  int tid = threadIdx.x, lane = tid & 63, w = tid >> 6;
  int i = blockIdx.x >> 2, jb = blockIdx.x & 3;
  size_t pos0 = (size_t)i * 512 + jb * 128;

  // ---- phase 1: z = LN(x) rows -> T; grab az fragments ----
  {
    int r = tid >> 1, hf = tid & 1;
    const float* px = x + pos0 * 128 + r * 128 + hf * 64;
    float4 xv[16];
    float s = 0.f, s2 = 0.f;
#pragma unroll
    for (int q = 0; q < 16; ++q) {
      xv[q] = *(const float4*)(px + q * 4);
      s += xv[q].x + xv[q].y + xv[q].z + xv[q].w;
      s2 += xv[q].x * xv[q].x + xv[q].y * xv[q].y + xv[q].z * xv[q].z + xv[q].w * xv[q].w;
    }
    s += __shfl_xor(s, 1);
    s2 += __shfl_xor(s2, 1);
    float mu = s * (1.f / 128.f);
    float rs = rsq_(s2 * (1.f / 128.f) - mu * mu + 1e-5f);
#pragma unroll
    for (int q = 0; q < 16; ++q) {
      int c0 = hf * 64 + q * 4;
      u16x4 o;
      o[0] = f2bf((xv[q].x - mu) * rs * zn_s[c0 + 0] + zn_b[c0 + 0]);
      o[1] = f2bf((xv[q].y - mu) * rs * zn_s[c0 + 1] + zn_b[c0 + 1]);
      o[2] = f2bf((xv[q].z - mu) * rs * zn_s[c0 + 2] + zn_b[c0 + 2]);
      o[3] = f2bf((xv[q].w - mu) * rs * zn_s[c0 + 3] + zn_b[c0 + 3]);
      *(u16x4*)&T[r * 136 + c0] = o;
    }
  }
  __syncthreads();
  bf16x8 az[2][4];
#pragma unroll
  for (int rf = 0; rf < 2; ++rf)
#pragma unroll
    for (int kf = 0; kf < 4; ++kf)
      az[rf][kf] = *(const bf16x8*)&T[(w * 32 + rf * 16 + (lane & 15)) * 136 + kf * 32 + (lane >> 4) * 8];
  __syncthreads();  // all az reads done before T is overwritten

  // ---- phase 2: transpose P[i][jb][h][jIn] (contiguous 32-KB slab) -> T[jIn][h] ----
  {
    int sh = tid & 15, sj = tid >> 4;
    const u16* src = P + ((size_t)i * 4 + jb) * 16384 + (sh * 8) * 128 + sj * 8;
    u16x8 vv[8];
#pragma unroll
    for (int e = 0; e < 8; ++e) vv[e] = *(const u16x8*)(src + e * 128);
#pragma unroll
    for (int f = 0; f < 8; ++f) {
      u16x8 ww;
#pragma unroll
      for (int e = 0; e < 8; ++e) ww[e] = vv[e][f];
      *(u16x8*)&T[(sj * 8 + f) * 136 + sh * 8] = ww;
    }
  }
  __syncthreads();

  // ---- LN over h, in place (2 threads per row) ----
  {
    int r = tid >> 1, hf = tid & 1;
    u16x8 vq[8];
    float s = 0.f, s2 = 0.f;
#pragma unroll
    for (int q = 0; q < 8; ++q) {
      vq[q] = *(const u16x8*)&T[r * 136 + hf * 64 + q * 8];
#pragma unroll
      for (int e = 0; e < 8; ++e) {
        float f = bf2f(vq[q][e]);
        s += f;
        s2 += f * f;
      }
    }
    s += __shfl_xor(s, 1);
    s2 += __shfl_xor(s2, 1);
    float mu = s * (1.f / 128.f);
    float rs = rsq_(s2 * (1.f / 128.f) - mu * mu + 1e-5f);
#pragma unroll
    for (int q = 0; q < 8; ++q) {
      u16x8 o;
#pragma unroll
      for (int e = 0; e < 8; ++e) {
        int hh = hf * 64 + q * 8 + e;
        o[e] = f2bf((bf2f(vq[q][e]) - mu) * rs * ln_s[hh] + ln_b[hh]);
      }
      *(u16x8*)&T[r * 136 + hf * 64 + q * 8] = o;
    }
  }
  __syncthreads();

  bf16x8 ap[2][4];
#pragma unroll
  for (int rf = 0; rf < 2; ++rf)
#pragma unroll
    for (int kf = 0; kf < 4; ++kf)
      ap[rf][kf] = *(const bf16x8*)&T[(w * 32 + rf * 16 + (lane & 15)) * 136 + kf * 32 + (lane >> 4) * 8];

  // ---- phase 3: MFMA with packed global weight fragments ----
  const u16* WgP = Wp + 4 * 16384 + lane * 8;
  const u16* WoP = Wp + 5 * 16384 + lane * 8;

#pragma unroll 2
  for (int sub = 0; sub < 4; ++sub) {
    f32x4 au[2][2], agg[2][2];
#pragma unroll
    for (int rf = 0; rf < 2; ++rf)
#pragma unroll
      for (int cf = 0; cf < 2; ++cf) {
        au[rf][cf] = f32x4{0.f, 0.f, 0.f, 0.f};
        agg[rf][cf] = f32x4{0.f, 0.f, 0.f, 0.f};
      }
#pragma unroll
    for (int cf = 0; cf < 2; ++cf) {
      int cg = sub * 2 + cf;
#pragma unroll
      for (int kf = 0; kf < 4; ++kf) {
        bf16x8 bo_f = *(const bf16x8*)&WoP[(cg * 4 + kf) * 512];
        bf16x8 bg_f = *(const bf16x8*)&WgP[(cg * 4 + kf) * 512];
#pragma unroll
        for (int rf = 0; rf < 2; ++rf) {
          au[rf][cf] = mfma16(ap[rf][kf], bo_f, au[rf][cf]);
          agg[rf][cf] = mfma16(az[rf][kf], bg_f, agg[rf][cf]);
        }
      }
    }
#pragma unroll
    for (int rf = 0; rf < 2; ++rf)
#pragma unroll
      for (int cf = 0; cf < 2; ++cf) {
        int d = sub * 32 + cf * 16 + (lane & 15);
        float bo_ = b_o[d], bg_ = b_g[d];
        int jl = w * 32 + rf * 16 + (lane >> 4) * 4;
#pragma unroll
        for (int r = 0; r < 4; ++r) {
          float uv = au[rf][cf][r] + bo_;
          out[(pos0 + jl + r) * 128 + d] = uv * sigmoidf_(agg[rf][cf][r] + bg_);
        }
      }
  }
}

extern "C" void kernel_launch(void* const* d_in, const int* in_sizes, int n_in,
                              void* d_out, int out_size, void* d_ws, size_t ws_size,
                              hipStream_t stream) {
  const float* x = (const float*)d_in[0];
  const float* zn_s = (const float*)d_in[1];
  const float* zn_b = (const float*)d_in[2];
  const float* ln_s = (const float*)d_in[3];
  const float* ln_b = (const float*)d_in[4];
  const float* w_a = (const float*)d_in[5];
  const float* b_a = (const float*)d_in[6];
  const float* w_ga = (const float*)d_in[7];
  const float* b_ga = (const float*)d_in[8];
  const float* w_b = (const float*)d_in[9];
  const float* b_b = (const float*)d_in[10];
  const float* w_gb = (const float*)d_in[11];
  const float* b_gb = (const float*)d_in[12];
  const float* w_o = (const float*)d_in[13];
  const float* b_o = (const float*)d_in[14];
  const float* w_g = (const float*)d_in[15];
  const float* b_g = (const float*)d_in[16];

  char* ws = (char*)d_ws;
  u16* n1t = (u16*)ws;                         // [4096][128][64] bf16, 64 MB
  u16* n2t = (u16*)(ws + 67108864);            // 64 MB
  u16* P = (u16*)(ws + 134217728);             // [512][4][128][128] bf16, 64 MB
  u16* Wp = (u16*)(ws + 201326592);            // packed 6x[128x128] bf16, 192 KB

  kW<<<192, 128, 0, stream>>>(w_a, w_ga, w_b, w_gb, w_g, w_o, Wp);
  kA<<<4096, 256, 0, stream>>>(x, zn_s, zn_b, b_a, b_ga, b_b, b_gb, Wp, n1t, n2t);
  kB<<<2048, 256, 0, stream>>>(n1t, n2t, P);
  kC<<<2048, 256, 0, stream>>>(x, P, zn_s, zn_b, ln_s, ln_b, Wp, b_o, b_g, (float*)d_out);
}

// Round 20
// 272.367 us; speedup vs baseline: 1.2970x; 1.2970x over previous
//
#include <hip/hip_runtime.h>

#define NSEQ 512
#define DD 128
#define NP (NSEQ * NSEQ)

typedef unsigned short u16;
typedef __attribute__((ext_vector_type(8))) unsigned short u16x8;
typedef __attribute__((ext_vector_type(4))) unsigned short u16x4;
typedef __attribute__((ext_vector_type(8))) short bf16x8;
typedef __attribute__((ext_vector_type(4))) float f32x4;

__device__ __forceinline__ u16 f2bf(float f) {
  unsigned int x = __float_as_uint(f);
  return (u16)((x + 0x7fffu + ((x >> 16) & 1u)) >> 16);  // RNE
}
__device__ __forceinline__ float bf2f(u16 u) {
  return __uint_as_float(((unsigned int)u) << 16);
}
__device__ __forceinline__ f32x4 mfma16(bf16x8 a, bf16x8 b, f32x4 c) {
  return __builtin_amdgcn_mfma_f32_16x16x32_bf16(a, b, c, 0, 0, 0);
}
__device__ __forceinline__ void gload16(const void* g, void* l) {
  __builtin_amdgcn_global_load_lds(
      (const __attribute__((address_space(1))) unsigned int*)g,
      (__attribute__((address_space(3))) unsigned int*)l, 16, 0, 0);
}
__device__ __forceinline__ float rcp_(float v) { return __builtin_amdgcn_rcpf(v); }
__device__ __forceinline__ float rsq_(float v) { return __builtin_amdgcn_rsqf(v); }
__device__ __forceinline__ float sigmoidf_(float v) { return rcp_(1.f + __expf(-v)); }

// Layouts:
//  n1t/n2t: [posblk][h][64]   (kA writes 16-KB contiguous per block)
//  P:       [i][jb][h][jIn]   (kC block (i,jb) reads ONE contiguous 32-KB slab)
//  kB stages its tile in LDS and streams rows as 256-B contiguous wave-stores.
// FINAL: round-15 configuration (verified twice: 272.5 / 272.7 us, absmax 0.0156).
// Ledger of falsified alternatives: z/gate handoffs to kC (r16/17: zero-sum or accuracy
// risk), unroll-2 ILP widening (r19: spills at the 56-64 VGPR allocation, kC +80 us),
// layout shuffles beyond these (r13/14: zero-sum between kB writes and kC reads).

// ---------------- weight prep: all six 128x128 matrices -> MFMA fragment order ----------
__global__ void kW(const float* __restrict__ wa, const float* __restrict__ wga,
                   const float* __restrict__ wb, const float* __restrict__ wgb,
                   const float* __restrict__ wg, const float* __restrict__ wo,
                   u16* __restrict__ Wp) {
  int b = blockIdx.x, t = threadIdx.x;
  int m = b >> 5, cf = (b >> 2) & 7, kf = b & 3;
  const float* m6[6] = {wa, wga, wb, wgb, wg, wo};
  const float* src = m6[m];
  int lane = t >> 1, e0 = (t & 1) * 4;
  u16* dst = Wp + m * 16384 + (cf * 4 + kf) * 512 + lane * 8 + e0;
  int col = cf * 16 + (lane & 15);
  int row0 = kf * 32 + (lane >> 4) * 8 + e0;
#pragma unroll
  for (int e = 0; e < 4; ++e) dst[e] = f2bf(src[(row0 + e) * 128 + col]);
}

// ---------------- kernel A: LN + 4 projections + gating -> n1t, n2t ------------------
__global__ void __launch_bounds__(256)
    __attribute__((amdgpu_waves_per_eu(4, 8)))
    kA(const float* __restrict__ x, const float* __restrict__ zn_s,
       const float* __restrict__ zn_b, const float* __restrict__ b_a,
       const float* __restrict__ b_ga, const float* __restrict__ b_b,
       const float* __restrict__ b_gb, const u16* __restrict__ Wp,
       u16* __restrict__ n1t, u16* __restrict__ n2t) {
  __shared__ __align__(16) u16 z[64 * 136];
  int tid = threadIdx.x;
  int pos0 = blockIdx.x * 64;
  int lane = tid & 63, w = tid >> 6;

  {  // single-pass LN: 4 threads per row (32 cols each), x held in registers
    int r = tid >> 2, part = tid & 3;
    const float* px = x + (size_t)pos0 * 128 + r * 128 + part * 32;
    float4 xv[8];
    float s = 0.f, s2 = 0.f;
#pragma unroll
    for (int q = 0; q < 8; ++q) {
      xv[q] = *(const float4*)(px + q * 4);
      s += xv[q].x + xv[q].y + xv[q].z + xv[q].w;
      s2 += xv[q].x * xv[q].x + xv[q].y * xv[q].y + xv[q].z * xv[q].z + xv[q].w * xv[q].w;
    }
    s += __shfl_xor(s, 1);
    s2 += __shfl_xor(s2, 1);
    s += __shfl_xor(s, 2);
    s2 += __shfl_xor(s2, 2);
    float mu = s * (1.f / 128.f);
    float rs = rsq_(s2 * (1.f / 128.f) - mu * mu + 1e-5f);
#pragma unroll
    for (int q = 0; q < 8; ++q) {
      int c0 = part * 32 + q * 4;
      u16x4 o;
      o[0] = f2bf((xv[q].x - mu) * rs * zn_s[c0 + 0] + zn_b[c0 + 0]);
      o[1] = f2bf((xv[q].y - mu) * rs * zn_s[c0 + 1] + zn_b[c0 + 1]);
      o[2] = f2bf((xv[q].z - mu) * rs * zn_s[c0 + 2] + zn_b[c0 + 2]);
      o[3] = f2bf((xv[q].w - mu) * rs * zn_s[c0 + 3] + zn_b[c0 + 3]);
      *(u16x4*)&z[r * 136 + c0] = o;
    }
  }
  __syncthreads();  // every wave reads all 64 z rows below

  int quad = lane >> 4, colL = lane & 15;
  size_t bbase = (size_t)blockIdx.x * 8192;  // this block's 16-KB output window

#pragma unroll 1
  for (int g = 0; g < 2; ++g) {
    const float* bxp = g ? b_b : b_a;
    const float* bgp = g ? b_gb : b_ga;
    u16* dst = g ? n2t : n1t;
    const u16* WxP = Wp + (g * 2) * 16384 + lane * 8;
    const u16* WgP = Wp + (g * 2 + 1) * 16384 + lane * 8;

    // hoisted: this wave's weight B-fragments (cf = 2w, 2w+1) and per-lane biases
    bf16x8 wxf[2][4], wgf[2][4];
    float bx[2], bg[2];
#pragma unroll
    for (int c2 = 0; c2 < 2; ++c2) {
      int cf = w * 2 + c2;
#pragma unroll
      for (int kf = 0; kf < 4; ++kf) {
        wxf[c2][kf] = *(const bf16x8*)&WxP[(cf * 4 + kf) * 512];
        wgf[c2][kf] = *(const bf16x8*)&WgP[(cf * 4 + kf) * 512];
      }
      int h = cf * 16 + colL;
      bx[c2] = bxp[h];
      bg[c2] = bgp[h];
    }

#pragma unroll 1
    for (int n = 0; n < 4; ++n) {
      bf16x8 zb[4];  // z A-fragments: row = n*16 + colL, k-chunk = quad
#pragma unroll
      for (int kf = 0; kf < 4; ++kf)
        zb[kf] = *(const bf16x8*)&z[(n * 16 + colL) * 136 + kf * 32 + quad * 8];
      f32x4 au0 = {0.f, 0.f, 0.f, 0.f}, au1 = au0, ag0 = au0, ag1 = au0;
#pragma unroll
      for (int kf = 0; kf < 4; ++kf) {
        au0 = mfma16(zb[kf], wxf[0][kf], au0);
        au1 = mfma16(zb[kf], wxf[1][kf], au1);
        ag0 = mfma16(zb[kf], wgf[0][kf], ag0);
        ag1 = mfma16(zb[kf], wgf[1][kf], ag1);
      }
      // D: row = quad*4 + r -> pos-in-block, col = colL -> h. [posblk][h][64] layout.
      int pin = n * 16 + quad * 4;
      int h0 = (w * 2) * 16 + colL;
      int h1 = (w * 2 + 1) * 16 + colL;
      u16x4 o0, o1;
#pragma unroll
      for (int r = 0; r < 4; ++r) {
        o0[r] = f2bf((au0[r] + bx[0]) * sigmoidf_(ag0[r] + bg[0]));
        o1[r] = f2bf((au1[r] + bx[1]) * sigmoidf_(ag1[r] + bg[1]));
      }
      *(u16x4*)&dst[bbase + h0 * 64 + pin] = o0;
      *(u16x4*)&dst[bbase + h1 * 64 + pin] = o1;
    }
  }
}

// ---------------- kernel B: per-h NT GEMM  P[i][jb][h][jIn] = sum_k n1.n2 ---------------
// LDS: SH[0..16383] = A double-buffer, SH[16384..32767] = B double-buffer; after the
// K-loop the whole 64 KB is dead and reused as the Pt staging tile [128][136].
__global__ __launch_bounds__(256) void kB(const u16* __restrict__ n1t,
                                          const u16* __restrict__ n2t,
                                          u16* __restrict__ P) {
  __shared__ __align__(16) u16 SH[32768];
  int bid = blockIdx.x;
  int h = bid >> 4, t = bid & 15;
  int i0 = (t >> 2) * 128, j0 = (t & 3) * 128, jb = t & 3;
  const u16* Ab = n1t + h * 64;
  const u16* Bb = n2t + h * 64;
  int tid = threadIdx.x, lane = tid & 63, w = tid >> 6;

  f32x4 acc[4][4];
#pragma unroll
  for (int a_ = 0; a_ < 4; ++a_)
#pragma unroll
    for (int b_ = 0; b_ < 4; ++b_) acc[a_][b_] = f32x4{0.f, 0.f, 0.f, 0.f};

  auto STAGE = [&](int buf, int kt) {
#pragma unroll
    for (int q = 0; q < 4; ++q) {
      int c = q * 256 + tid;
      int row = c >> 3, ch = c & 7;
      int chG = ch ^ (row & 7);
      gload16(Ab + (size_t)((i0 + row) * 8 + kt) * 8192 + chG * 8, &SH[buf * 8192 + c * 8]);
    }
#pragma unroll
    for (int q = 0; q < 4; ++q) {
      int c = q * 256 + tid;
      int row = c >> 3, ch = c & 7;
      int chG = ch ^ (row & 7);
      gload16(Bb + (size_t)((j0 + row) * 8 + kt) * 8192 + chG * 8,
              &SH[16384 + buf * 8192 + c * 8]);
    }
  };

  STAGE(0, 0);
  int cur = 0;
  int r0 = (w >> 1) * 64, c0 = (w & 1) * 64;
#pragma unroll 1
  for (int kt = 0; kt < 8; ++kt) {
    if (kt < 7) {
      STAGE(cur ^ 1, kt + 1);
      __builtin_amdgcn_sched_barrier(0);
      asm volatile("s_waitcnt vmcnt(8)" ::: "memory");
    } else {
      asm volatile("s_waitcnt vmcnt(0)" ::: "memory");
    }
    __builtin_amdgcn_sched_barrier(0);
    __builtin_amdgcn_s_barrier();
    __builtin_amdgcn_sched_barrier(0);
#pragma unroll
    for (int kf = 0; kf < 2; ++kf) {
      bf16x8 a[4], b[4];
#pragma unroll
      for (int rf = 0; rf < 4; ++rf) {
        int row = r0 + rf * 16 + (lane & 15);
        a[rf] = *(const bf16x8*)&SH[cur * 8192 + row * 64 +
                                    (((kf * 4 + (lane >> 4)) ^ (row & 7)) * 8)];
      }
#pragma unroll
      for (int cf = 0; cf < 4; ++cf) {
        int row = c0 + cf * 16 + (lane & 15);
        b[cf] = *(const bf16x8*)&SH[16384 + cur * 8192 + row * 64 +
                                    (((kf * 4 + (lane >> 4)) ^ (row & 7)) * 8)];
      }
#pragma unroll
      for (int rf = 0; rf < 4; ++rf)
#pragma unroll
        for (int cf = 0; cf < 4; ++cf) acc[rf][cf] = mfma16(a[rf], b[cf], acc[rf][cf]);
    }
    __builtin_amdgcn_sched_barrier(0);
    __builtin_amdgcn_s_barrier();
    __builtin_amdgcn_sched_barrier(0);
    cur ^= 1;
  }

  // ---- epilogue: stage tile in LDS, then stream 256-B contiguous wave-stores ----
#pragma unroll
  for (int rf = 0; rf < 4; ++rf)
#pragma unroll
    for (int cf = 0; cf < 4; ++cf) {
      int lrow = (w >> 1) * 64 + rf * 16 + (lane >> 4) * 4;
      int jIn = c0 + cf * 16 + (lane & 15);
#pragma unroll
      for (int r = 0; r < 4; ++r) SH[(lrow + r) * 136 + jIn] = f2bf(acc[rf][cf][r]);
    }
  __syncthreads();
#pragma unroll 1
  for (int lr8 = 0; lr8 < 32; ++lr8) {
    int lr = w * 32 + lr8;
    unsigned int v = *(const unsigned int*)&SH[lr * 136 + lane * 2];
    *(unsigned int*)&P[((size_t)(i0 + lr) * 4 + jb) * 16384 + h * 128 + lane * 2] = v;
  }
}

// ---------------- kernel C: LN over h, @w_o + b_o, * sigmoid(z@w_g + b_g) -----------------
__global__ void __launch_bounds__(256)
    __attribute__((amdgpu_waves_per_eu(4, 4)))
    kC(const float* __restrict__ x, const u16* __restrict__ P,
       const float* __restrict__ zn_s, const float* __restrict__ zn_b,
       const float* __restrict__ ln_s, const float* __restrict__ ln_b,
       const u16* __restrict__ Wp, const float* __restrict__ b_o,
       const float* __restrict__ b_g, float* __restrict__ out) {
  __shared__ __align__(16) u16 T[128 * 136];
  int tid = threadIdx.x, lane = tid & 63, w = tid >> 6;
  int i = blockIdx.x >> 2, jb = blockIdx.x & 3;
  size_t pos0 = (size_t)i * 512 + jb * 128;

  // ---- phase 1: z = LN(x) rows -> T; grab az fragments ----
  {
    int r = tid >> 1, hf = tid & 1;
    const float* px = x + pos0 * 128 + r * 128 + hf * 64;
    float4 xv[16];
    float s = 0.f, s2 = 0.f;
#pragma unroll
    for (int q = 0; q < 16; ++q) {
      xv[q] = *(const float4*)(px + q * 4);
      s += xv[q].x + xv[q].y + xv[q].z + xv[q].w;
      s2 += xv[q].x * xv[q].x + xv[q].y * xv[q].y + xv[q].z * xv[q].z + xv[q].w * xv[q].w;
    }
    s += __shfl_xor(s, 1);
    s2 += __shfl_xor(s2, 1);
    float mu = s * (1.f / 128.f);
    float rs = rsq_(s2 * (1.f / 128.f) - mu * mu + 1e-5f);
#pragma unroll
    for (int q = 0; q < 16; ++q) {
      int c0 = hf * 64 + q * 4;
      u16x4 o;
      o[0] = f2bf((xv[q].x - mu) * rs * zn_s[c0 + 0] + zn_b[c0 + 0]);
      o[1] = f2bf((xv[q].y - mu) * rs * zn_s[c0 + 1] + zn_b[c0 + 1]);
      o[2] = f2bf((xv[q].z - mu) * rs * zn_s[c0 + 2] + zn_b[c0 + 2]);
      o[3] = f2bf((xv[q].w - mu) * rs * zn_s[c0 + 3] + zn_b[c0 + 3]);
      *(u16x4*)&T[r * 136 + c0] = o;
    }
  }
  __syncthreads();
  bf16x8 az[2][4];
#pragma unroll
  for (int rf = 0; rf < 2; ++rf)
#pragma unroll
    for (int kf = 0; kf < 4; ++kf)
      az[rf][kf] = *(const bf16x8*)&T[(w * 32 + rf * 16 + (lane & 15)) * 136 + kf * 32 + (lane >> 4) * 8];
  __syncthreads();  // all az reads done before T is overwritten

  // ---- phase 2: transpose P[i][jb][h][jIn] (contiguous 32-KB slab) -> T[jIn][h] ----
  {
    int sh = tid & 15, sj = tid >> 4;
    const u16* src = P + ((size_t)i * 4 + jb) * 16384 + (sh * 8) * 128 + sj * 8;
    u16x8 vv[8];
#pragma unroll
    for (int e = 0; e < 8; ++e) vv[e] = *(const u16x8*)(src + e * 128);
#pragma unroll
    for (int f = 0; f < 8; ++f) {
      u16x8 ww;
#pragma unroll
      for (int e = 0; e < 8; ++e) ww[e] = vv[e][f];
      *(u16x8*)&T[(sj * 8 + f) * 136 + sh * 8] = ww;
    }
  }
  __syncthreads();

  // ---- LN over h, in place (2 threads per row) ----
  {
    int r = tid >> 1, hf = tid & 1;
    u16x8 vq[8];
    float s = 0.f, s2 = 0.f;
#pragma unroll
    for (int q = 0; q < 8; ++q) {
      vq[q] = *(const u16x8*)&T[r * 136 + hf * 64 + q * 8];
#pragma unroll
      for (int e = 0; e < 8; ++e) {
        float f = bf2f(vq[q][e]);
        s += f;
        s2 += f * f;
      }
    }
    s += __shfl_xor(s, 1);
    s2 += __shfl_xor(s2, 1);
    float mu = s * (1.f / 128.f);
    float rs = rsq_(s2 * (1.f / 128.f) - mu * mu + 1e-5f);
#pragma unroll
    for (int q = 0; q < 8; ++q) {
      u16x8 o;
#pragma unroll
      for (int e = 0; e < 8; ++e) {
        int hh = hf * 64 + q * 8 + e;
        o[e] = f2bf((bf2f(vq[q][e]) - mu) * rs * ln_s[hh] + ln_b[hh]);
      }
      *(u16x8*)&T[r * 136 + hf * 64 + q * 8] = o;
    }
  }
  __syncthreads();

  bf16x8 ap[2][4];
#pragma unroll
  for (int rf = 0; rf < 2; ++rf)
#pragma unroll
    for (int kf = 0; kf < 4; ++kf)
      ap[rf][kf] = *(const bf16x8*)&T[(w * 32 + rf * 16 + (lane & 15)) * 136 + kf * 32 + (lane >> 4) * 8];

  // ---- phase 3: MFMA with packed global weight fragments ----
  const u16* WgP = Wp + 4 * 16384 + lane * 8;
  const u16* WoP = Wp + 5 * 16384 + lane * 8;

#pragma unroll 1
  for (int sub = 0; sub < 4; ++sub) {
    f32x4 au[2][2], agg[2][2];
#pragma unroll
    for (int rf = 0; rf < 2; ++rf)
#pragma unroll
      for (int cf = 0; cf < 2; ++cf) {
        au[rf][cf] = f32x4{0.f, 0.f, 0.f, 0.f};
        agg[rf][cf] = f32x4{0.f, 0.f, 0.f, 0.f};
      }
#pragma unroll
    for (int cf = 0; cf < 2; ++cf) {
      int cg = sub * 2 + cf;
#pragma unroll
      for (int kf = 0; kf < 4; ++kf) {
        bf16x8 bo_f = *(const bf16x8*)&WoP[(cg * 4 + kf) * 512];
        bf16x8 bg_f = *(const bf16x8*)&WgP[(cg * 4 + kf) * 512];
#pragma unroll
        for (int rf = 0; rf < 2; ++rf) {
          au[rf][cf] = mfma16(ap[rf][kf], bo_f, au[rf][cf]);
          agg[rf][cf] = mfma16(az[rf][kf], bg_f, agg[rf][cf]);
        }
      }
    }
#pragma unroll
    for (int rf = 0; rf < 2; ++rf)
#pragma unroll
      for (int cf = 0; cf < 2; ++cf) {
        int d = sub * 32 + cf * 16 + (lane & 15);
        float bo_ = b_o[d], bg_ = b_g[d];
        int jl = w * 32 + rf * 16 + (lane >> 4) * 4;
#pragma unroll
        for (int r = 0; r < 4; ++r) {
          float uv = au[rf][cf][r] + bo_;
          out[(pos0 + jl + r) * 128 + d] = uv * sigmoidf_(agg[rf][cf][r] + bg_);
        }
      }
  }
}

extern "C" void kernel_launch(void* const* d_in, const int* in_sizes, int n_in,
                              void* d_out, int out_size, void* d_ws, size_t ws_size,
                              hipStream_t stream) {
  const float* x = (const float*)d_in[0];
  const float* zn_s = (const float*)d_in[1];
  const float* zn_b = (const float*)d_in[2];
  const float* ln_s = (const float*)d_in[3];
  const float* ln_b = (const float*)d_in[4];
  const float* w_a = (const float*)d_in[5];
  const float* b_a = (const float*)d_in[6];
  const float* w_ga = (const float*)d_in[7];
  const float* b_ga = (const float*)d_in[8];
  const float* w_b = (const float*)d_in[9];
  const float* b_b = (const float*)d_in[10];
  const float* w_gb = (const float*)d_in[11];
  const float* b_gb = (const float*)d_in[12];
  const float* w_o = (const float*)d_in[13];
  const float* b_o = (const float*)d_in[14];
  const float* w_g = (const float*)d_in[15];
  const float* b_g = (const float*)d_in[16];

  char* ws = (char*)d_ws;
  u16* n1t = (u16*)ws;                         // [4096][128][64] bf16, 64 MB
  u16* n2t = (u16*)(ws + 67108864);            // 64 MB
  u16* P = (u16*)(ws + 134217728);             // [512][4][128][128] bf16, 64 MB
  u16* Wp = (u16*)(ws + 201326592);            // packed 6x[128x128] bf16, 192 KB

  kW<<<192, 128, 0, stream>>>(w_a, w_ga, w_b, w_gb, w_g, w_o, Wp);
  kA<<<4096, 256, 0, stream>>>(x, zn_s, zn_b, b_a, b_ga, b_b, b_gb, Wp, n1t, n2t);
  kB<<<2048, 256, 0, stream>>>(n1t, n2t, P);
  kC<<<2048, 256, 0, stream>>>(x, P, zn_s, zn_b, ln_s, ln_b, Wp, b_o, b_g, (float*)d_out);
}